// Round 2
// baseline (945.249 us; speedup 1.0000x reference)
//
#include <hip/hip_runtime.h>
#include <math.h>

#define NB 16
#define PP 2500
#define WWD 50
#define NANCH 22500
#define CIN 512
#define PRE 6000
#define POST 300
#define NW64 94          // ceil(6000/64): 94*64 = 6016 bits
#define NW32 188
#define SORTN 8192

// d_out float offsets (elements)
#define OFF_LOCS   0
#define OFF_SCORES 1440000
#define OFF_ROIS   2160000
#define OFF_ROIIX  2179200
#define OFF_ANCH   2184000

typedef unsigned long long u64;
typedef unsigned u32;

// ---- anchor for row r: f32-faithful to _enumerate_anchors (f64 base -> f32, f32 add) ----
__device__ inline float4 anchor_of(int r) {
    int p = r / 9, a = r - p * 9;
    int gy = p / WWD, gx = p - gy * WWD;
    int ri = a / 3, si = a - ri * 3;
    double ratio = (ri == 0) ? 0.5 : (ri == 1 ? 1.0 : 2.0);
    double scale = (si == 0) ? 8.0 : (si == 1 ? 16.0 : 32.0);
    double hh = 16.0 * scale * sqrt(ratio);
    double wd = 16.0 * scale * sqrt(1.0 / ratio);
    float by1 = (float)(8.0 - hh * 0.5);
    float bx1 = (float)(8.0 - wd * 0.5);
    float by2 = (float)(8.0 + hh * 0.5);
    float bx2 = (float)(8.0 + wd * 0.5);
    float sy = (float)gy * 16.0f, sx = (float)gx * 16.0f;
    return make_float4(sy + by1, sx + bx1, sy + by2, sx + bx2);
}

// ---- decode + clip + min-size: f32-faithful to _loc2bbox/_propose_one ----
__device__ inline float4 decode_box(const float* __restrict__ lp, float4 an,
                                    float ih, float iw, bool* ok) {
    float dy = lp[0], dx = lp[1], dh = lp[2], dw = lp[3];
    float h = an.z - an.x, w = an.w - an.y;
    float cy = an.x + 0.5f * h, cx = an.y + 0.5f * w;
    float ny = dy * h + cy, nx = dx * w + cx;
    float nh = expf(dh) * h, nw = expf(dw) * w;
    float y1 = fminf(fmaxf(ny - 0.5f * nh, 0.f), ih);
    float x1 = fminf(fmaxf(nx - 0.5f * nw, 0.f), iw);
    float y2 = fminf(fmaxf(ny + 0.5f * nh, 0.f), ih);
    float x2 = fminf(fmaxf(nx + 0.5f * nw, 0.f), iw);
    *ok = ((y2 - y1) >= 16.0f) && ((x2 - x1) >= 16.0f);
    return make_float4(y1, x1, y2, x2);
}

// ---------------- Kernel 1: relu + dual 1x1 conv (f32, jax-faithful) ----------------
__global__ __launch_bounds__(256) void k_gemm(
    const float* __restrict__ x, const float* __restrict__ lw, const float* __restrict__ lb,
    const float* __restrict__ sw, const float* __restrict__ sb, float* __restrict__ out)
{
    const int TP = 64, CK = 32;
    __shared__ float xs[CK][TP];     // 8 KB
    __shared__ float wsh[56][CK];    // 7 KB
    int b  = blockIdx.x / 40;
    int pb = (blockIdx.x % 40) * TP;
    int tid = threadIdx.x;
    int po = tid & 63;
    int og = tid >> 6;               // wave-uniform
    int o0 = og * 14;
    int cnt = (og == 3) ? 12 : 14;
    float acc[14];
#pragma unroll
    for (int k = 0; k < 14; ++k) acc[k] = 0.f;
    const float* xb = x + (size_t)b * (CIN * PP);

    for (int c0 = 0; c0 < CIN; c0 += CK) {
#pragma unroll
        for (int it = 0; it < (CK * TP) / 256; ++it) {
            int lin = it * 256 + tid;
            int cc = lin >> 6, p = lin & 63;
            int gp = pb + p;
            float v = (gp < PP) ? xb[(size_t)(c0 + cc) * PP + gp] : 0.f;
            xs[cc][p] = fmaxf(v, 0.f);               // relu fused
        }
        for (int lin = tid; lin < 54 * CK; lin += 256) {
            int o = lin >> 5, cc = lin & 31;
            wsh[o][cc] = (o < 36) ? lw[o * CIN + c0 + cc] : sw[(o - 36) * CIN + c0 + cc];
        }
        __syncthreads();
        float xv[CK];
#pragma unroll
        for (int cc = 0; cc < CK; ++cc) xv[cc] = xs[cc][po];
#pragma unroll
        for (int k = 0; k < 14; ++k) {
            if (k < cnt) {
                float a = acc[k];
                const float* wr = &wsh[o0 + k][0];
#pragma unroll
                for (int cc = 0; cc < CK; ++cc) a += xv[cc] * wr[cc];
                acc[k] = a;
            }
        }
        __syncthreads();
    }

    int p = pb + po;
    if (p >= PP) return;
#pragma unroll
    for (int k = 0; k < 14; ++k) {
        if (k < cnt) {
            int o = o0 + k;
            if (o < 36)
                out[(size_t)OFF_LOCS + ((size_t)b * PP + p) * 36 + o] = acc[k] + lb[o];
            else
                out[(size_t)OFF_SCORES + ((size_t)b * PP + p) * 18 + (o - 36)] = acc[k] + sb[o - 36];
        }
    }
}

// ---------------- Kernel 2: anchors + softmax-fg + decode + sort keys ----------------
__global__ void k_keys(const float* __restrict__ out_ro, u64* __restrict__ keys,
                       float* __restrict__ out, const int* __restrict__ imh_p,
                       const int* __restrict__ imw_p)
{
    int g = blockIdx.x * blockDim.x + threadIdx.x;
    if (g >= NB * NANCH) return;
    int b = g / NANCH;
    int r = g - b * NANCH;
    int p = r / 9, a = r - p * 9;

    float4 an = anchor_of(r);
    if (b == 0) ((float4*)(out + OFF_ANCH))[r] = an;

    float ih = (float)imh_p[0], iw = (float)imw_p[0];
    bool ok;
    (void)decode_box(out_ro + (size_t)OFF_LOCS + (size_t)g * 4, an, ih, iw, &ok);

    // fg = softmax(scores)[...,1], f32-faithful
    const float* sp = out_ro + (size_t)OFF_SCORES + ((size_t)b * PP + p) * 18 + a * 2;
    float s0 = sp[0], s1 = sp[1];
    float mx = fmaxf(s0, s1);
    float e0 = expf(s0 - mx), e1 = expf(s1 - mx);
    float fg = e1 / (e0 + e1);

    float sc = ok ? fg : -INFINITY;
    u32 sb = __float_as_uint(sc);
    sb = (sb & 0x80000000u) ? ~sb : (sb | 0x80000000u);
    // primary: f32 score (monotone map); secondary: smaller index first
    u64 key = ((u64)sb << 32) | (u64)(u32)(NANCH - r);
    keys[g] = key;
}

// ---------------- Kernel 3: per-batch exact top-6000 (radix select + bitonic sort) ----------------
__global__ __launch_bounds__(1024) void k_select(
    const u64* __restrict__ keys, const float* __restrict__ out_ro,
    float* __restrict__ topBoxes, u32* __restrict__ topValid,
    const int* __restrict__ imh_p, const int* __restrict__ imw_p)
{
    __shared__ u64 sk[SORTN];        // 64 KB
    __shared__ u32 hist[256];
    __shared__ u64 shp;
    __shared__ int shk;
    __shared__ int scnt;
    int b = blockIdx.x, tid = threadIdx.x;
    const u64* kb = keys + (size_t)b * NANCH;

    u64 prefix = 0ull, pmask = 0ull;
    int k = PRE;
    for (int shift = 56; shift >= 0; shift -= 8) {
        if (tid < 256) hist[tid] = 0u;
        __syncthreads();
        for (int i = tid; i < NANCH; i += 1024) {
            u64 key = kb[i];
            if ((key & pmask) == prefix)
                atomicAdd(&hist[(u32)(key >> shift) & 255u], 1u);
        }
        __syncthreads();
        if (tid == 0) {
            int accu = 0;
            for (int bin = 255; bin >= 0; --bin) {
                int c = (int)hist[bin];
                if (accu + c >= k) { shp = prefix | ((u64)bin << shift); shk = k - accu; break; }
                accu += c;
            }
            scnt = 0;
        }
        __syncthreads();
        prefix = shp; k = shk; pmask |= (0xFFull << shift);
        __syncthreads();
    }
    // compact the exactly-6000 keys >= pivot (keys unique per batch)
    for (int i = tid; i < NANCH; i += 1024) {
        u64 key = kb[i];
        if (key >= prefix) {
            int pos = atomicAdd(&scnt, 1);
            if (pos < SORTN) sk[pos] = key;
        }
    }
    __syncthreads();
    int c0 = min(scnt, SORTN);
    for (int i = c0 + tid; i < SORTN; i += 1024) sk[i] = 0ull;
    __syncthreads();
    // bitonic sort, descending
    for (int kk = 2; kk <= SORTN; kk <<= 1) {
        for (int j = kk >> 1; j > 0; j >>= 1) {
            for (int i = tid; i < SORTN; i += 1024) {
                int ij = i ^ j;
                if (ij > i) {
                    u64 va = sk[i], vb = sk[ij];
                    bool up = ((i & kk) == 0);
                    if (up ? (va < vb) : (va > vb)) { sk[i] = vb; sk[ij] = va; }
                }
            }
            __syncthreads();
        }
    }
    // emit: gather loc, re-decode (same f32 path), write boxes + validity
    float ih = (float)imh_p[0], iw = (float)imw_p[0];
    for (int rr = tid; rr < PRE; rr += 1024) {
        u64 key = sk[rr];
        bool valid = (key >> 63) != 0ull;       // valid keys have mapped sign bit set
        int idx = valid ? (NANCH - (int)(key & 0xFFFFull)) : 0;
        bool ok;
        float4 an = anchor_of(idx);
        float4 bx = decode_box(out_ro + (size_t)OFF_LOCS + ((size_t)b * NANCH + idx) * 4,
                               an, ih, iw, &ok);
        ((float4*)topBoxes)[(size_t)b * PRE + rr] = bx;
        topValid[(size_t)b * PRE + rr] = valid ? 1u : 0u;
    }
}

// ---------------- Kernel 4: greedy NMS (boxes in LDS), early stop at 300 kept ----------------
__global__ __launch_bounds__(1024) void k_nms(const float* __restrict__ topBoxes,
                                              const u32* __restrict__ topValid,
                                              float* __restrict__ out)
{
    __shared__ float4 bxs[PRE];          // 96 KB
    __shared__ u32 sup[NW32];
    __shared__ int keptList[POST];
    int b = blockIdx.x, tid = threadIdx.x;

    for (int i = tid; i < NW32; i += 1024) sup[i] = 0u;
    for (int r = tid; r < PRE; r += 1024)
        bxs[r] = ((const float4*)topBoxes)[(size_t)b * PRE + r];
    __syncthreads();
    for (int r = tid; r < PRE; r += 1024)
        if (!topValid[(size_t)b * PRE + r]) atomicOr(&sup[r >> 5], 1u << (r & 31));
    if (tid == 0) atomicOr(&sup[187], 0xFFFF0000u);   // bits 6000..6015
    __syncthreads();

    int nk = 0;
    int wave = tid >> 6, lane = tid & 63;
    for (int w = 0; w < NW64; ++w) {
        u64 m = ~(((u64)sup[2 * w + 1] << 32) | (u64)sup[2 * w]);
        while (m) {
            int i = w * 64 + __builtin_ctzll(m);
            __syncthreads();                 // everyone has read sup; writers may start
            if (tid == 0) { keptList[nk] = i; atomicOr(&sup[i >> 5], 1u << (i & 31)); }
            nk++;
            if (nk >= POST) break;
            float4 bi = bxs[i];
            float ia = (bi.z - bi.x) * (bi.w - bi.y);
            for (int wsi = w + wave; wsi < NW64; wsi += 16) {
                int j = wsi * 64 + lane;
                bool s = false;
                if (j < PRE) {
                    float4 bj = bxs[j];
                    float ty1 = fmaxf(bi.x, bj.x), tx1 = fmaxf(bi.y, bj.y);
                    float ty2 = fminf(bi.z, bj.z), tx2 = fminf(bi.w, bj.w);
                    float inter = fmaxf(ty2 - ty1, 0.f) * fmaxf(tx2 - tx1, 0.f);
                    float ja = (bj.z - bj.x) * (bj.w - bj.y);
                    float iou = inter / fmaxf(ia + ja - inter, 1e-9f);
                    s = iou > 0.7f;
                }
                u64 bal = __ballot(s);
                if (lane == 0 && bal) {
                    atomicOr(&sup[2 * wsi], (u32)bal);
                    atomicOr(&sup[2 * wsi + 1], (u32)(bal >> 32));
                }
            }
            __syncthreads();
            m = ~(((u64)sup[2 * w + 1] << 32) | (u64)sup[2 * w]);
            unsigned sh = (unsigned)(i & 63);
            m = (sh == 63) ? 0ull : (m & (~0ull << (sh + 1)));
        }
        if (nk >= POST) break;
    }
    __syncthreads();
    for (int r = tid; r < POST; r += 1024) {
        float4 v = make_float4(0.f, 0.f, 0.f, 0.f);
        if (r < nk) v = bxs[keptList[r]];
        ((float4*)(out + OFF_ROIS))[(size_t)b * POST + r] = v;
        out[(size_t)OFF_ROIIX + (size_t)b * POST + r] = (float)b;
    }
}

// ---------------- launch ----------------
extern "C" void kernel_launch(void* const* d_in, const int* in_sizes, int n_in,
                              void* d_out, int out_size, void* d_ws, size_t ws_size,
                              hipStream_t stream) {
    const float* x  = (const float*)d_in[0];
    const int* imh  = (const int*)d_in[1];
    const int* imw  = (const int*)d_in[2];
    // d_in[3]=conv1_w, d_in[4]=conv1_b: unused by the reference
    const float* sw = (const float*)d_in[5];
    const float* sb = (const float*)d_in[6];
    const float* lw = (const float*)d_in[7];
    const float* lb = (const float*)d_in[8];
    float* out = (float*)d_out;
    char* wsb = (char*)d_ws;

    u64*   keys     = (u64*)(wsb);                    // 2,880,000 B
    float* topBoxes = (float*)(wsb + 2880000);        // 1,536,000 B
    u32*   topValid = (u32*)(wsb + 4416000);          //   384,000 B  (total 4.8 MB)

    hipLaunchKernelGGL(k_gemm, dim3(NB * 40), dim3(256), 0, stream,
                       x, lw, lb, sw, sb, out);
    hipLaunchKernelGGL(k_keys, dim3((NB * NANCH + 255) / 256), dim3(256), 0, stream,
                       out, keys, out, imh, imw);
    hipLaunchKernelGGL(k_select, dim3(NB), dim3(1024), 0, stream,
                       keys, out, topBoxes, topValid, imh, imw);
    hipLaunchKernelGGL(k_nms, dim3(NB), dim3(1024), 0, stream,
                       topBoxes, topValid, out);
}

// Round 3
// 488.217 us; speedup vs baseline: 1.9361x; 1.9361x over previous
//
#include <hip/hip_runtime.h>
#include <math.h>

#define NB 16
#define PP 2500
#define WWD 50
#define NANCH 22500
#define CIN 512
#define PRE 6000
#define POST 300
#define NW64 94          // ceil(6000/64): 94*64 = 6016 bits
#define NW32 188
#define SORTN 8192

// d_out float offsets (elements)
#define OFF_LOCS   0
#define OFF_SCORES 1440000
#define OFF_ROIS   2160000
#define OFF_ROIIX  2179200
#define OFF_ANCH   2184000

typedef unsigned long long u64;
typedef unsigned u32;

// ---- anchor for row r: f32-faithful to _enumerate_anchors (f64 base -> f32, f32 add) ----
__device__ inline float4 anchor_of(int r) {
    int p = r / 9, a = r - p * 9;
    int gy = p / WWD, gx = p - gy * WWD;
    int ri = a / 3, si = a - ri * 3;
    double ratio = (ri == 0) ? 0.5 : (ri == 1 ? 1.0 : 2.0);
    double scale = (si == 0) ? 8.0 : (si == 1 ? 16.0 : 32.0);
    double hh = 16.0 * scale * sqrt(ratio);
    double wd = 16.0 * scale * sqrt(1.0 / ratio);
    float by1 = (float)(8.0 - hh * 0.5);
    float bx1 = (float)(8.0 - wd * 0.5);
    float by2 = (float)(8.0 + hh * 0.5);
    float bx2 = (float)(8.0 + wd * 0.5);
    float sy = (float)gy * 16.0f, sx = (float)gx * 16.0f;
    return make_float4(sy + by1, sx + bx1, sy + by2, sx + bx2);
}

// ---- decode + clip + min-size: f32-faithful to _loc2bbox/_propose_one ----
__device__ inline float4 decode_box(const float* __restrict__ lp, float4 an,
                                    float ih, float iw, bool* ok) {
    float dy = lp[0], dx = lp[1], dh = lp[2], dw = lp[3];
    float h = an.z - an.x, w = an.w - an.y;
    float cy = an.x + 0.5f * h, cx = an.y + 0.5f * w;
    float ny = dy * h + cy, nx = dx * w + cx;
    float nh = expf(dh) * h, nw = expf(dw) * w;
    float y1 = fminf(fmaxf(ny - 0.5f * nh, 0.f), ih);
    float x1 = fminf(fmaxf(nx - 0.5f * nw, 0.f), iw);
    float y2 = fminf(fmaxf(ny + 0.5f * nh, 0.f), ih);
    float x2 = fminf(fmaxf(nx + 0.5f * nw, 0.f), iw);
    *ok = ((y2 - y1) >= 16.0f) && ((x2 - x1) >= 16.0f);
    return make_float4(y1, x1, y2, x2);
}

__device__ inline float iou_f32(float4 a, float4 b) {
    float ty1 = fmaxf(a.x, b.x), tx1 = fmaxf(a.y, b.y);
    float ty2 = fminf(a.z, b.z), tx2 = fminf(a.w, b.w);
    float inter = fmaxf(ty2 - ty1, 0.f) * fmaxf(tx2 - tx1, 0.f);
    float aa = (a.z - a.x) * (a.w - a.y);
    float ab = (b.z - b.x) * (b.w - b.y);
    return inter / fmaxf(aa + ab - inter, 1e-9f);
}

// ---------------- Kernel 1: relu + dual 1x1 conv (f32, jax-faithful) ----------------
__global__ __launch_bounds__(256) void k_gemm(
    const float* __restrict__ x, const float* __restrict__ lw, const float* __restrict__ lb,
    const float* __restrict__ sw, const float* __restrict__ sb, float* __restrict__ out)
{
    const int TP = 64, CK = 32;
    __shared__ float xs[CK][TP];     // 8 KB
    __shared__ float wsh[56][CK];    // 7 KB
    int b  = blockIdx.x / 40;
    int pb = (blockIdx.x % 40) * TP;
    int tid = threadIdx.x;
    int po = tid & 63;
    int og = tid >> 6;               // wave-uniform
    int o0 = og * 14;
    int cnt = (og == 3) ? 12 : 14;
    float acc[14];
#pragma unroll
    for (int k = 0; k < 14; ++k) acc[k] = 0.f;
    const float* xb = x + (size_t)b * (CIN * PP);

    for (int c0 = 0; c0 < CIN; c0 += CK) {
#pragma unroll
        for (int it = 0; it < (CK * TP) / 256; ++it) {
            int lin = it * 256 + tid;
            int cc = lin >> 6, p = lin & 63;
            int gp = pb + p;
            float v = (gp < PP) ? xb[(size_t)(c0 + cc) * PP + gp] : 0.f;
            xs[cc][p] = fmaxf(v, 0.f);               // relu fused
        }
        for (int lin = tid; lin < 54 * CK; lin += 256) {
            int o = lin >> 5, cc = lin & 31;
            wsh[o][cc] = (o < 36) ? lw[o * CIN + c0 + cc] : sw[(o - 36) * CIN + c0 + cc];
        }
        __syncthreads();
        float xv[CK];
#pragma unroll
        for (int cc = 0; cc < CK; ++cc) xv[cc] = xs[cc][po];
#pragma unroll
        for (int k = 0; k < 14; ++k) {
            if (k < cnt) {
                float a = acc[k];
                const float* wr = &wsh[o0 + k][0];
#pragma unroll
                for (int cc = 0; cc < CK; ++cc) a += xv[cc] * wr[cc];
                acc[k] = a;
            }
        }
        __syncthreads();
    }

    int p = pb + po;
    if (p >= PP) return;
#pragma unroll
    for (int k = 0; k < 14; ++k) {
        if (k < cnt) {
            int o = o0 + k;
            if (o < 36)
                out[(size_t)OFF_LOCS + ((size_t)b * PP + p) * 36 + o] = acc[k] + lb[o];
            else
                out[(size_t)OFF_SCORES + ((size_t)b * PP + p) * 18 + (o - 36)] = acc[k] + sb[o - 36];
        }
    }
}

// ---------------- Kernel 2: anchors + softmax-fg + sort keys ----------------
__global__ void k_keys(const float* __restrict__ out_ro, u64* __restrict__ keys,
                       float* __restrict__ out, const int* __restrict__ imh_p,
                       const int* __restrict__ imw_p)
{
    int g = blockIdx.x * blockDim.x + threadIdx.x;
    if (g >= NB * NANCH) return;
    int b = g / NANCH;
    int r = g - b * NANCH;
    int p = r / 9, a = r - p * 9;

    float4 an = anchor_of(r);
    if (b == 0) ((float4*)(out + OFF_ANCH))[r] = an;

    float ih = (float)imh_p[0], iw = (float)imw_p[0];
    bool ok;
    (void)decode_box(out_ro + (size_t)OFF_LOCS + (size_t)g * 4, an, ih, iw, &ok);

    // fg = softmax(scores)[...,1], f32-faithful
    const float* sp = out_ro + (size_t)OFF_SCORES + ((size_t)b * PP + p) * 18 + a * 2;
    float s0 = sp[0], s1 = sp[1];
    float mx = fmaxf(s0, s1);
    float e0 = expf(s0 - mx), e1 = expf(s1 - mx);
    float fg = e1 / (e0 + e1);

    float sc = ok ? fg : -INFINITY;
    u32 sb = __float_as_uint(sc);
    sb = (sb & 0x80000000u) ? ~sb : (sb | 0x80000000u);
    // primary: f32 score (monotone map); secondary: smaller index first
    u64 key = ((u64)sb << 32) | (u64)(u32)(NANCH - r);
    keys[g] = key;
}

// ---------------- Kernel 3: per-batch exact top-6000 (radix select + bitonic sort) ----------------
__global__ __launch_bounds__(1024) void k_select(
    const u64* __restrict__ keys, const float* __restrict__ out_ro,
    float* __restrict__ topBoxes, u32* __restrict__ topValid,
    const int* __restrict__ imh_p, const int* __restrict__ imw_p)
{
    __shared__ u64 sk[SORTN];        // 64 KB
    __shared__ u32 hist[256];
    __shared__ u64 shp;
    __shared__ int shk;
    __shared__ int scnt;
    int b = blockIdx.x, tid = threadIdx.x;
    const u64* kb = keys + (size_t)b * NANCH;

    u64 prefix = 0ull, pmask = 0ull;
    int k = PRE;
    for (int shift = 56; shift >= 0; shift -= 8) {
        if (tid < 256) hist[tid] = 0u;
        __syncthreads();
        for (int i = tid; i < NANCH; i += 1024) {
            u64 key = kb[i];
            if ((key & pmask) == prefix)
                atomicAdd(&hist[(u32)(key >> shift) & 255u], 1u);
        }
        __syncthreads();
        if (tid == 0) {
            int accu = 0;
            for (int bin = 255; bin >= 0; --bin) {
                int c = (int)hist[bin];
                if (accu + c >= k) { shp = prefix | ((u64)bin << shift); shk = k - accu; break; }
                accu += c;
            }
            scnt = 0;
        }
        __syncthreads();
        prefix = shp; k = shk; pmask |= (0xFFull << shift);
        __syncthreads();
    }
    // compact the exactly-6000 keys >= pivot (keys unique per batch)
    for (int i = tid; i < NANCH; i += 1024) {
        u64 key = kb[i];
        if (key >= prefix) {
            int pos = atomicAdd(&scnt, 1);
            if (pos < SORTN) sk[pos] = key;
        }
    }
    __syncthreads();
    int c0 = min(scnt, SORTN);
    for (int i = c0 + tid; i < SORTN; i += 1024) sk[i] = 0ull;
    __syncthreads();
    // bitonic sort, descending
    for (int kk = 2; kk <= SORTN; kk <<= 1) {
        for (int j = kk >> 1; j > 0; j >>= 1) {
            for (int i = tid; i < SORTN; i += 1024) {
                int ij = i ^ j;
                if (ij > i) {
                    u64 va = sk[i], vb = sk[ij];
                    bool up = ((i & kk) == 0);
                    if (up ? (va < vb) : (va > vb)) { sk[i] = vb; sk[ij] = va; }
                }
            }
            __syncthreads();
        }
    }
    // emit: gather loc, re-decode (same f32 path), write boxes + validity
    float ih = (float)imh_p[0], iw = (float)imw_p[0];
    for (int rr = tid; rr < PRE; rr += 1024) {
        u64 key = sk[rr];
        bool valid = (key >> 63) != 0ull;       // valid keys have mapped sign bit set
        int idx = valid ? (NANCH - (int)(key & 0xFFFFull)) : 0;
        bool ok;
        float4 an = anchor_of(idx);
        float4 bx = decode_box(out_ro + (size_t)OFF_LOCS + ((size_t)b * NANCH + idx) * 4,
                               an, ih, iw, &ok);
        ((float4*)topBoxes)[(size_t)b * PRE + rr] = bx;
        topValid[(size_t)b * PRE + rr] = valid ? 1u : 0u;
    }
}

// ---------------- Kernel 4: lazy/JIT greedy NMS, early stop at 300 kept ----------------
// Per chunk of 64 rows: (JIT) all 16 waves test the chunk's rows against the kept
// list so far; (A) wave 0 serially resolves the chunk via ballot. Rows past the
// 300th kept are never touched.
__global__ __launch_bounds__(1024) void k_nms(const float* __restrict__ topBoxes,
                                              const u32* __restrict__ topValid,
                                              float* __restrict__ out)
{
    __shared__ float4 chunkB[64];
    __shared__ float4 keptB[POST];
    __shared__ u32 sup[NW32];
    __shared__ int s_nk;
    __shared__ int s_stop;
    int b = blockIdx.x, tid = threadIdx.x;
    int wave = tid >> 6, lane = tid & 63;
    const float4* tb = (const float4*)topBoxes + (size_t)b * PRE;

    for (int i = tid; i < NW32; i += 1024) sup[i] = 0u;
    if (tid == 0) { s_nk = 0; s_stop = 0; }
    __syncthreads();
    for (int r = tid; r < PRE; r += 1024)
        if (!topValid[(size_t)b * PRE + r]) atomicOr(&sup[r >> 5], 1u << (r & 31));
    if (tid == 0) atomicOr(&sup[187], 0xFFFF0000u);   // bits 6000..6015 invalid
    __syncthreads();

    for (int c = 0; c < NW64; ++c) {
        int base = c * 64;
        // stage chunk boxes for phase A
        if (tid < 64)
            chunkB[tid] = (base + tid < PRE) ? tb[base + tid]
                                             : make_float4(0.f, 0.f, 0.f, 0.f);
        // ---- JIT: suppress this chunk's rows vs kept list so far ----
        int nk0 = s_nk;
        bool s = false;
        if (nk0 > 0 && base + lane < PRE) {
            float4 bj = tb[base + lane];
            for (int t = wave; t < nk0; t += 16)
                s |= iou_f32(keptB[t], bj) > 0.7f;
        }
        u64 bal = __ballot(s);
        if (lane == 0 && bal) {
            atomicOr(&sup[2 * c], (u32)bal);
            atomicOr(&sup[2 * c + 1], (u32)(bal >> 32));
        }
        __syncthreads();
        // ---- phase A: wave 0 resolves chunk serially ----
        if (wave == 0) {
            u64 avail = ~(((u64)sup[2 * c + 1] << 32) | (u64)sup[2 * c]);
            float4 myB = chunkB[lane];
            int nkl = s_nk;
            while (avail && nkl < POST) {
                int i = __builtin_ctzll(avail);
                float4 bi = chunkB[i];
                if (lane == 0) keptB[nkl] = bi;
                nkl++;
                bool ss = iou_f32(bi, myB) > 0.7f;
                u64 bb = __ballot(ss);
                avail &= ~((1ull << i) | bb);
            }
            if (lane == 0) { s_nk = nkl; if (nkl >= POST) s_stop = 1; }
        }
        __syncthreads();
        if (s_stop) break;
    }

    __syncthreads();
    int nk = min(s_nk, POST);
    for (int r = tid; r < POST; r += 1024) {
        float4 v = make_float4(0.f, 0.f, 0.f, 0.f);
        if (r < nk) v = keptB[r];
        ((float4*)(out + OFF_ROIS))[(size_t)b * POST + r] = v;
        out[(size_t)OFF_ROIIX + (size_t)b * POST + r] = (float)b;
    }
}

// ---------------- launch ----------------
extern "C" void kernel_launch(void* const* d_in, const int* in_sizes, int n_in,
                              void* d_out, int out_size, void* d_ws, size_t ws_size,
                              hipStream_t stream) {
    const float* x  = (const float*)d_in[0];
    const int* imh  = (const int*)d_in[1];
    const int* imw  = (const int*)d_in[2];
    // d_in[3]=conv1_w, d_in[4]=conv1_b: unused by the reference
    const float* sw = (const float*)d_in[5];
    const float* sb = (const float*)d_in[6];
    const float* lw = (const float*)d_in[7];
    const float* lb = (const float*)d_in[8];
    float* out = (float*)d_out;
    char* wsb = (char*)d_ws;

    u64*   keys     = (u64*)(wsb);                    // 2,880,000 B
    float* topBoxes = (float*)(wsb + 2880000);        // 1,536,000 B
    u32*   topValid = (u32*)(wsb + 4416000);          //   384,000 B  (total 4.8 MB)

    hipLaunchKernelGGL(k_gemm, dim3(NB * 40), dim3(256), 0, stream,
                       x, lw, lb, sw, sb, out);
    hipLaunchKernelGGL(k_keys, dim3((NB * NANCH + 255) / 256), dim3(256), 0, stream,
                       out, keys, out, imh, imw);
    hipLaunchKernelGGL(k_select, dim3(NB), dim3(1024), 0, stream,
                       keys, out, topBoxes, topValid, imh, imw);
    hipLaunchKernelGGL(k_nms, dim3(NB), dim3(1024), 0, stream,
                       topBoxes, topValid, out);
}

// Round 4
// 301.522 us; speedup vs baseline: 3.1349x; 1.6192x over previous
//
#include <hip/hip_runtime.h>
#include <math.h>

#define NB 16
#define PP 2500
#define WWD 50
#define NANCH 22500
#define CIN 512
#define PRE 6000
#define POST 300
#define NW64 94          // ceil(6000/64): 94*64 = 6016 bits
#define NW32 188
#define SEG 2816         // per-segment rows (8 segs: 8*2816 = 22528 >= 22500)
#define SEGP 4096        // padded power-of-2
#define RUN 6016         // truncated run length after merges (rank-safe > 6000)

// d_out float offsets (elements)
#define OFF_LOCS   0
#define OFF_SCORES 1440000
#define OFF_ROIS   2160000
#define OFF_ROIIX  2179200
#define OFF_ANCH   2184000

typedef unsigned long long u64;
typedef unsigned u32;

// ---- anchor for row r: f32-faithful to _enumerate_anchors (f64 base -> f32, f32 add) ----
__device__ inline float4 anchor_of(int r) {
    int p = r / 9, a = r - p * 9;
    int gy = p / WWD, gx = p - gy * WWD;
    int ri = a / 3, si = a - ri * 3;
    double ratio = (ri == 0) ? 0.5 : (ri == 1 ? 1.0 : 2.0);
    double scale = (si == 0) ? 8.0 : (si == 1 ? 16.0 : 32.0);
    double hh = 16.0 * scale * sqrt(ratio);
    double wd = 16.0 * scale * sqrt(1.0 / ratio);
    float by1 = (float)(8.0 - hh * 0.5);
    float bx1 = (float)(8.0 - wd * 0.5);
    float by2 = (float)(8.0 + hh * 0.5);
    float bx2 = (float)(8.0 + wd * 0.5);
    float sy = (float)gy * 16.0f, sx = (float)gx * 16.0f;
    return make_float4(sy + by1, sx + bx1, sy + by2, sx + bx2);
}

// ---- decode + clip + min-size: f32-faithful to _loc2bbox/_propose_one ----
__device__ inline float4 decode_box(const float* __restrict__ lp, float4 an,
                                    float ih, float iw, bool* ok) {
    float dy = lp[0], dx = lp[1], dh = lp[2], dw = lp[3];
    float h = an.z - an.x, w = an.w - an.y;
    float cy = an.x + 0.5f * h, cx = an.y + 0.5f * w;
    float ny = dy * h + cy, nx = dx * w + cx;
    float nh = expf(dh) * h, nw = expf(dw) * w;
    float y1 = fminf(fmaxf(ny - 0.5f * nh, 0.f), ih);
    float x1 = fminf(fmaxf(nx - 0.5f * nw, 0.f), iw);
    float y2 = fminf(fmaxf(ny + 0.5f * nh, 0.f), ih);
    float x2 = fminf(fmaxf(nx + 0.5f * nw, 0.f), iw);
    *ok = ((y2 - y1) >= 16.0f) && ((x2 - x1) >= 16.0f);
    return make_float4(y1, x1, y2, x2);
}

__device__ inline float iou_f32(float4 a, float4 b) {
    float ty1 = fmaxf(a.x, b.x), tx1 = fmaxf(a.y, b.y);
    float ty2 = fminf(a.z, b.z), tx2 = fminf(a.w, b.w);
    float inter = fmaxf(ty2 - ty1, 0.f) * fmaxf(tx2 - tx1, 0.f);
    float aa = (a.z - a.x) * (a.w - a.y);
    float ab = (b.z - b.x) * (b.w - b.y);
    return inter / fmaxf(aa + ab - inter, 1e-9f);
}

// ---------------- Kernel 1: relu + dual 1x1 conv (f32, jax-faithful) ----------------
__global__ __launch_bounds__(256) void k_gemm(
    const float* __restrict__ x, const float* __restrict__ lw, const float* __restrict__ lb,
    const float* __restrict__ sw, const float* __restrict__ sb, float* __restrict__ out)
{
    const int TP = 64, CK = 32;
    __shared__ float xs[CK][TP];     // 8 KB
    __shared__ float wsh[56][CK];    // 7 KB
    int b  = blockIdx.x / 40;
    int pb = (blockIdx.x % 40) * TP;
    int tid = threadIdx.x;
    int po = tid & 63;
    int og = tid >> 6;               // wave-uniform
    int o0 = og * 14;
    int cnt = (og == 3) ? 12 : 14;
    float acc[14];
#pragma unroll
    for (int k = 0; k < 14; ++k) acc[k] = 0.f;
    const float* xb = x + (size_t)b * (CIN * PP);

    for (int c0 = 0; c0 < CIN; c0 += CK) {
#pragma unroll
        for (int it = 0; it < (CK * TP) / 256; ++it) {
            int lin = it * 256 + tid;
            int cc = lin >> 6, p = lin & 63;
            int gp = pb + p;
            float v = (gp < PP) ? xb[(size_t)(c0 + cc) * PP + gp] : 0.f;
            xs[cc][p] = fmaxf(v, 0.f);               // relu fused
        }
        for (int lin = tid; lin < 54 * CK; lin += 256) {
            int o = lin >> 5, cc = lin & 31;
            wsh[o][cc] = (o < 36) ? lw[o * CIN + c0 + cc] : sw[(o - 36) * CIN + c0 + cc];
        }
        __syncthreads();
        float xv[CK];
#pragma unroll
        for (int cc = 0; cc < CK; ++cc) xv[cc] = xs[cc][po];
#pragma unroll
        for (int k = 0; k < 14; ++k) {
            if (k < cnt) {
                float a = acc[k];
                const float* wr = &wsh[o0 + k][0];
#pragma unroll
                for (int cc = 0; cc < CK; ++cc) a += xv[cc] * wr[cc];
                acc[k] = a;
            }
        }
        __syncthreads();
    }

    int p = pb + po;
    if (p >= PP) return;
#pragma unroll
    for (int k = 0; k < 14; ++k) {
        if (k < cnt) {
            int o = o0 + k;
            if (o < 36)
                out[(size_t)OFF_LOCS + ((size_t)b * PP + p) * 36 + o] = acc[k] + lb[o];
            else
                out[(size_t)OFF_SCORES + ((size_t)b * PP + p) * 18 + (o - 36)] = acc[k] + sb[o - 36];
        }
    }
}

// ---------------- Kernel 2: per-segment key-gen + bitonic sort (desc) ----------------
// grid = NB*8, 1024 threads. Fuses softmax-fg, min-size, anchor write (b==0),
// key build; sorts 4096 keys in LDS; writes one descending run per block.
__global__ __launch_bounds__(1024) void k_sort1(
    const float* __restrict__ out_ro, float* __restrict__ out, u64* __restrict__ runs,
    const int* __restrict__ imh_p, const int* __restrict__ imw_p)
{
    __shared__ u64 sk[SEGP];         // 32 KB
    int blk = blockIdx.x;
    int b = blk >> 3, s = blk & 7;
    int tid = threadIdx.x;
    int base = s * SEG;
    float ih = (float)imh_p[0], iw = (float)imw_p[0];

    for (int i = tid; i < SEGP; i += 1024) {
        int r = base + i;
        u64 key = 0ull;
        if (i < SEG && r < NANCH) {
            float4 an = anchor_of(r);
            if (b == 0) ((float4*)(out + OFF_ANCH))[r] = an;
            bool ok;
            (void)decode_box(out_ro + (size_t)OFF_LOCS + ((size_t)b * NANCH + r) * 4,
                             an, ih, iw, &ok);
            int p = r / 9, a = r - p * 9;
            const float* sp = out_ro + (size_t)OFF_SCORES + ((size_t)b * PP + p) * 18 + a * 2;
            float s0 = sp[0], s1 = sp[1];
            float mx = fmaxf(s0, s1);
            float e0 = expf(s0 - mx), e1 = expf(s1 - mx);
            float fg = e1 / (e0 + e1);
            float sc = ok ? fg : -INFINITY;
            u32 sb = __float_as_uint(sc);
            sb = (sb & 0x80000000u) ? ~sb : (sb | 0x80000000u);
            key = ((u64)sb << 32) | (u64)(u32)(NANCH - r);   // unique; idx-asc tiebreak
        }
        sk[i] = key;
    }
    __syncthreads();
    // bitonic sort, descending
    for (int kk = 2; kk <= SEGP; kk <<= 1) {
        for (int j = kk >> 1; j > 0; j >>= 1) {
            for (int i = tid; i < SEGP; i += 1024) {
                int ij = i ^ j;
                if (ij > i) {
                    u64 va = sk[i], vb = sk[ij];
                    bool up = ((i & kk) == 0);
                    if (up ? (va < vb) : (va > vb)) { sk[i] = vb; sk[ij] = va; }
                }
            }
            __syncthreads();
        }
    }
    u64* dst = runs + (size_t)blk * SEGP;
    for (int i = tid; i < SEGP; i += 1024) dst[i] = sk[i];
}

// ---------------- merge-path pairwise merge (descending, unique keys) ----------------
__device__ inline int mp_search(const u64* __restrict__ A, const u64* __restrict__ B,
                                int LA, int LB, int d) {
    int lo = max(0, d - LB), hi = min(d, LA);
    while (lo < hi) {
        int mid = (lo + hi) >> 1;
        if (A[mid] > B[d - 1 - mid]) lo = mid + 1; else hi = mid;
    }
    return lo;
}

__global__ __launch_bounds__(1024) void k_merge(
    const u64* __restrict__ in, u64* __restrict__ outk,
    int runLen, int pairsPerBatch, int outLen)
{
    int blk = blockIdx.x;
    int b = blk / pairsPerBatch, m = blk - b * pairsPerBatch;
    const u64* A = in + ((size_t)b * pairsPerBatch * 2 + 2 * m) * runLen;
    const u64* B = A + runLen;
    u64* C = outk + ((size_t)b * pairsPerBatch + m) * outLen;
    int E = (outLen + 1023) >> 10;
    int d0 = threadIdx.x * E;
    if (d0 >= outLen) return;
    int cnt = min(E, outLen - d0);
    int i = mp_search(A, B, runLen, runLen, d0);
    int j = d0 - i;
    for (int e = 0; e < cnt; ++e) {
        u64 va = (i < runLen) ? A[i] : 0ull;
        u64 vb = (j < runLen) ? B[j] : 0ull;
        bool takeA = (j >= runLen) || ((i < runLen) && (va > vb));
        C[d0 + e] = takeA ? va : vb;
        if (takeA) ++i; else ++j;
    }
}

// ---------------- final merge + emit boxes (top-6000, sorted) ----------------
__global__ __launch_bounds__(1024) void k_merge_emit(
    const u64* __restrict__ in, const float* __restrict__ out_ro,
    float* __restrict__ topBoxes, u32* __restrict__ topValid,
    const int* __restrict__ imh_p, const int* __restrict__ imw_p)
{
    int b = blockIdx.x;
    const u64* A = in + (size_t)b * 2 * RUN;
    const u64* B = A + RUN;
    float ih = (float)imh_p[0], iw = (float)imw_p[0];
    int E = (PRE + 1023) >> 10;   // 6
    int d0 = threadIdx.x * E;
    if (d0 >= PRE) return;
    int cnt = min(E, PRE - d0);
    int i = mp_search(A, B, RUN, RUN, d0);
    int j = d0 - i;
    for (int e = 0; e < cnt; ++e) {
        u64 va = (i < RUN) ? A[i] : 0ull;
        u64 vb = (j < RUN) ? B[j] : 0ull;
        bool takeA = (j >= RUN) || ((i < RUN) && (va > vb));
        u64 key = takeA ? va : vb;
        if (takeA) ++i; else ++j;
        int d = d0 + e;
        bool valid = (key >> 63) != 0ull;
        int idx = valid ? (NANCH - (int)(key & 0xFFFFFFFFull)) : 0;
        bool ok;
        float4 an = anchor_of(idx);
        float4 bx = decode_box(out_ro + (size_t)OFF_LOCS + ((size_t)b * NANCH + idx) * 4,
                               an, ih, iw, &ok);
        ((float4*)topBoxes)[(size_t)b * PRE + d] = bx;
        topValid[(size_t)b * PRE + d] = valid ? 1u : 0u;
    }
}

// ---------------- Kernel 4: lazy/JIT greedy NMS, early stop at 300 kept ----------------
__global__ __launch_bounds__(1024) void k_nms(const float* __restrict__ topBoxes,
                                              const u32* __restrict__ topValid,
                                              float* __restrict__ out)
{
    __shared__ float4 chunkB[64];
    __shared__ float4 keptB[POST];
    __shared__ u32 sup[NW32];
    __shared__ int s_nk;
    __shared__ int s_stop;
    int b = blockIdx.x, tid = threadIdx.x;
    int wave = tid >> 6, lane = tid & 63;
    const float4* tb = (const float4*)topBoxes + (size_t)b * PRE;

    for (int i = tid; i < NW32; i += 1024) sup[i] = 0u;
    if (tid == 0) { s_nk = 0; s_stop = 0; }
    __syncthreads();
    for (int r = tid; r < PRE; r += 1024)
        if (!topValid[(size_t)b * PRE + r]) atomicOr(&sup[r >> 5], 1u << (r & 31));
    if (tid == 0) atomicOr(&sup[187], 0xFFFF0000u);   // bits 6000..6015 invalid
    __syncthreads();

    for (int c = 0; c < NW64; ++c) {
        int base = c * 64;
        if (tid < 64)
            chunkB[tid] = (base + tid < PRE) ? tb[base + tid]
                                             : make_float4(0.f, 0.f, 0.f, 0.f);
        // ---- JIT: suppress this chunk's rows vs kept list so far ----
        int nk0 = s_nk;
        bool s = false;
        if (nk0 > 0 && base + lane < PRE) {
            float4 bj = tb[base + lane];
            for (int t = wave; t < nk0; t += 16)
                s |= iou_f32(keptB[t], bj) > 0.7f;
        }
        u64 bal = __ballot(s);
        if (lane == 0 && bal) {
            atomicOr(&sup[2 * c], (u32)bal);
            atomicOr(&sup[2 * c + 1], (u32)(bal >> 32));
        }
        __syncthreads();
        // ---- phase A: wave 0 resolves chunk serially ----
        if (wave == 0) {
            u64 avail = ~(((u64)sup[2 * c + 1] << 32) | (u64)sup[2 * c]);
            float4 myB = chunkB[lane];
            int nkl = s_nk;
            while (avail && nkl < POST) {
                int i = __builtin_ctzll(avail);
                float4 bi = chunkB[i];
                if (lane == 0) keptB[nkl] = bi;
                nkl++;
                bool ss = iou_f32(bi, myB) > 0.7f;
                u64 bb = __ballot(ss);
                avail &= ~((1ull << i) | bb);
            }
            if (lane == 0) { s_nk = nkl; if (nkl >= POST) s_stop = 1; }
        }
        __syncthreads();
        if (s_stop) break;
    }

    __syncthreads();
    int nk = min(s_nk, POST);
    for (int r = tid; r < POST; r += 1024) {
        float4 v = make_float4(0.f, 0.f, 0.f, 0.f);
        if (r < nk) v = keptB[r];
        ((float4*)(out + OFF_ROIS))[(size_t)b * POST + r] = v;
        out[(size_t)OFF_ROIIX + (size_t)b * POST + r] = (float)b;
    }
}

// ---------------- launch ----------------
extern "C" void kernel_launch(void* const* d_in, const int* in_sizes, int n_in,
                              void* d_out, int out_size, void* d_ws, size_t ws_size,
                              hipStream_t stream) {
    const float* x  = (const float*)d_in[0];
    const int* imh  = (const int*)d_in[1];
    const int* imw  = (const int*)d_in[2];
    // d_in[3]=conv1_w, d_in[4]=conv1_b: unused by the reference
    const float* sw = (const float*)d_in[5];
    const float* sb = (const float*)d_in[6];
    const float* lw = (const float*)d_in[7];
    const float* lb = (const float*)d_in[8];
    float* out = (float*)d_out;
    char* wsb = (char*)d_ws;

    u64*   runs0    = (u64*)(wsb);                     // 16*8*4096*8  = 4,194,304 B
    u64*   runs1    = (u64*)(wsb + 4194304);           // 16*4*6016*8  = 3,080,192 B
    u64*   runs2    = (u64*)(wsb + 7274496);           // 16*2*6016*8  = 1,540,096 B
    float* topBoxes = (float*)(wsb + 8814592);         // 16*6000*16   = 1,536,000 B
    u32*   topValid = (u32*)(wsb + 10350592);          // 16*6000*4    =   384,000 B

    hipLaunchKernelGGL(k_gemm, dim3(NB * 40), dim3(256), 0, stream,
                       x, lw, lb, sw, sb, out);
    hipLaunchKernelGGL(k_sort1, dim3(NB * 8), dim3(1024), 0, stream,
                       out, out, runs0, imh, imw);
    hipLaunchKernelGGL(k_merge, dim3(NB * 4), dim3(1024), 0, stream,
                       runs0, runs1, SEGP, 4, RUN);
    hipLaunchKernelGGL(k_merge, dim3(NB * 2), dim3(1024), 0, stream,
                       runs1, runs2, RUN, 2, RUN);
    hipLaunchKernelGGL(k_merge_emit, dim3(NB), dim3(1024), 0, stream,
                       runs2, out, topBoxes, topValid, imh, imw);
    hipLaunchKernelGGL(k_nms, dim3(NB), dim3(1024), 0, stream,
                       topBoxes, topValid, out);
}